// Round 11
// baseline (280.990 us; speedup 1.0000x reference)
//
#include <hip/hip_runtime.h>
#include <hip/hip_bf16.h>

// GraphConv: out = verts@W0^T + b0 + scatter_sum_undirected(verts@W1^T + b1)
// V=100000, E=1000000, D=64. fp32 in/out; edges int64 (or int32) detected.
//
// R10 -> R11: fill still had 7x write amplification (WRITE 92MB vs ~13MB of
// col data): each XCD sub-grid streamed all 16MB of edges through its L2,
// evicting partially-filled col lines. Now two-phase:
//   Phase A (bin): blocks take contiguous edge chunks, LDS-aggregate bucket
//     counts, 1 global atomic per (block,bucket), write packed 4B entries
//     ((t-vlo)<<17 | n) sequentially into 8 per-XCD bins (16.8MB).
//   Phase B (fill): XCD x reads only ITS 2MB bin -> cnt/col lines stay
//     L2-resident; clean full-line evictions only.
// bins alias sums (bins dead before gather writes sums).

#define NV 100000
#define NE 1000000
#define DIM 64
#define CAP 64
#define SPILL_MAX 65536
#define NXCD 8
#define VPERX ((NV + NXCD - 1) / NXCD)   // 12500 vertices per XCD partition
#define NTILE (NV / 16)                  // 6250 MFMA row-tiles
#define CAPB 525000                      // bin capacity (exp 500k, +38 sigma)
#define ABLK 2048
#define CHUNK ((NE + ABLK - 1) / ABLK)   // 489 edges per phase-A block

typedef __attribute__((ext_vector_type(8))) short short8;   // 8 bf16
typedef __attribute__((ext_vector_type(4))) float f32x4;

// ---------------------------------------------------------------------------
// Edge-layout detection. int64 words: [a_lo,a_hi,b_lo,b_hi,...], hi==0 always.
// int32 words: odd words random in [0,V). 64 zero odd words => int64.
// ---------------------------------------------------------------------------
__global__ void detect_kernel(const int* __restrict__ edges, int* __restrict__ flag) {
    int v = edges[2 * threadIdx.x + 1];
    unsigned long long any = __ballot(v != 0);
    if (threadIdx.x == 0) *flag = (any == 0ull) ? 1 : 0;  // 1 = int64 layout
}

__device__ __forceinline__ unsigned f2bf1(float f) {  // RNE fp32 -> bf16 bits
    unsigned u = __float_as_uint(f);
    return (u + 0x7fffu + ((u >> 16) & 1u)) >> 16;
}

__device__ __forceinline__ short8 pack_bf8(float4 a, float4 b) {
    short8 r;
    r[0] = (short)f2bf1(a.x); r[1] = (short)f2bf1(a.y);
    r[2] = (short)f2bf1(a.z); r[3] = (short)f2bf1(a.w);
    r[4] = (short)f2bf1(b.x); r[5] = (short)f2bf1(b.y);
    r[6] = (short)f2bf1(b.z); r[7] = (short)f2bf1(b.w);
    return r;
}

// verts (fp32) -> vbf (bf16-packed rows, 2 features per uint, 128 B/row)
__global__ void prep_kernel(const float* __restrict__ verts, uint2* __restrict__ vbf) {
    long i = (long)blockIdx.x * blockDim.x + threadIdx.x;
    if (i < (long)NV * (DIM / 4)) {
        float4 v = ((const float4*)verts)[i];
        uint2 w;
        w.x = f2bf1(v.x) | (f2bf1(v.y) << 16);
        w.y = f2bf1(v.z) | (f2bf1(v.w) << 16);
        vbf[i] = w;
    }
}

// ---------------------------------------------------------------------------
// Phase A: bin directed endpoints by target partition. Entry = (t_local<<17)|n
// (t_local < 12500 -> 14 bits; n < 100000 -> 17 bits). Per-block LDS count ->
// one global atomic per bucket -> sequential packed writes.
// ---------------------------------------------------------------------------
__global__ __launch_bounds__(256)
void bin_kernel(const int* __restrict__ edges, unsigned* __restrict__ bins,
                int* __restrict__ bcur, const int* __restrict__ flag) {
    __shared__ int lcnt[NXCD], lbase[NXCD];
    const bool is64 = (*flag != 0);
    const int tid = threadIdx.x;
    const long lo = (long)blockIdx.x * CHUNK;
    const long hi = (lo + CHUNK < NE) ? lo + CHUNK : NE;

    if (tid < NXCD) lcnt[tid] = 0;
    __syncthreads();

    for (long e = lo + tid; e < hi; e += 256) {
        int a, b;
        if (is64) { int4 q = ((const int4*)edges)[e]; a = q.x; b = q.z; }
        else      { int2 q = ((const int2*)edges)[e]; a = q.x; b = q.y; }
        atomicAdd(&lcnt[a / VPERX], 1);
        atomicAdd(&lcnt[b / VPERX], 1);
    }
    __syncthreads();
    if (tid < NXCD) lbase[tid] = atomicAdd(&bcur[tid], lcnt[tid]);
    __syncthreads();
    if (tid < NXCD) lcnt[tid] = 0;      // reuse as local cursor
    __syncthreads();

    for (long e = lo + tid; e < hi; e += 256) {
        int a, b;
        if (is64) { int4 q = ((const int4*)edges)[e]; a = q.x; b = q.z; }
        else      { int2 q = ((const int2*)edges)[e]; a = q.x; b = q.y; }
        const int pa = a / VPERX, pb = b / VPERX;
        int ia = lbase[pa] + atomicAdd(&lcnt[pa], 1);
        if (ia < CAPB) bins[(long)pa * CAPB + ia] =
            ((unsigned)(a - pa * VPERX) << 17) | (unsigned)b;
        int ib = lbase[pb] + atomicAdd(&lcnt[pb], 1);
        if (ib < CAPB) bins[(long)pb * CAPB + ib] =
            ((unsigned)(b - pb * VPERX) << 17) | (unsigned)a;
    }
}

__device__ __forceinline__ void push_edge(int t, int n, int* cnt, int* col,
                                          int* spill, int* nspill) {
    int p = atomicAdd(&cnt[t], 1);
    if (p < CAP) {
        col[t * CAP + p] = n;
    } else {
        int sp = atomicAdd(nspill, 1);
        if (sp < SPILL_MAX) { spill[2 * sp] = t; spill[2 * sp + 1] = n; }
    }
}

// Phase B: XCD x's 256-block sub-grid consumes ONLY bucket x (2MB, L2-hot).
__global__ __launch_bounds__(256)
void fill_kernel(const unsigned* __restrict__ bins, const int* __restrict__ bcur,
                 int* __restrict__ cnt, int* __restrict__ col,
                 int* __restrict__ spill, int* __restrict__ nspill) {
    const int xcd = blockIdx.x & (NXCD - 1);
    const int sub = blockIdx.x >> 3;
    const int nsub = gridDim.x >> 3;
    const int vlo = xcd * VPERX;
    int nent = bcur[xcd]; if (nent > CAPB) nent = CAPB;
    const unsigned* mybin = bins + (long)xcd * CAPB;
    const long stride = (long)nsub * blockDim.x;

    for (long i = (long)sub * blockDim.x + threadIdx.x; i < nent; i += stride) {
        const unsigned e = mybin[i];
        push_edge(vlo + (int)(e >> 17), (int)(e & 0x1FFFFu), cnt, col, spill, nspill);
    }
}

__device__ __forceinline__ void acc4(float4& a, uint2 w) {
    a.x += __uint_as_float(w.x << 16);
    a.y += __uint_as_float(w.x & 0xffff0000u);
    a.z += __uint_as_float(w.y << 16);
    a.w += __uint_as_float(w.y & 0xffff0000u);
}

// One wave per vertex; 16 rows in flight (R6-fixed: no shfl under divergence).
__global__ __launch_bounds__(256)
void gather_kernel(const uint2* __restrict__ vbf, const int* __restrict__ cnt,
                   const int* __restrict__ col, float* __restrict__ sums) {
    const int lane = threadIdx.x & 63;
    const int sub = lane & 15;
    const int grp = lane >> 4;
    const int v = (int)((blockIdx.x * blockDim.x + threadIdx.x) >> 6);
    if (v >= NV) return;

    int dg = cnt[v]; if (dg > CAP) dg = CAP;
    const int myc = col[v * CAP + lane];

    float4 a0 = {0.f, 0.f, 0.f, 0.f}, a1 = a0, a2 = a0, a3 = a0;
    int j = 0;
    for (; j + 16 <= dg; j += 16) {
        const int i0 = j + grp;
        const int c0 = __shfl(myc, i0, 64);
        const int c1 = __shfl(myc, i0 + 4, 64);
        const int c2 = __shfl(myc, i0 + 8, 64);
        const int c3 = __shfl(myc, i0 + 12, 64);
        const uint2 w0 = vbf[(long)c0 * 16 + sub];
        const uint2 w1 = vbf[(long)c1 * 16 + sub];
        const uint2 w2 = vbf[(long)c2 * 16 + sub];
        const uint2 w3 = vbf[(long)c3 * 16 + sub];
        acc4(a0, w0); acc4(a1, w1); acc4(a2, w2); acc4(a3, w3);
    }
#pragma unroll
    for (int t = 0; t < 4; ++t) {
        const int ii = j + grp + 4 * t;
        const int c = __shfl(myc, ii < 63 ? ii : 63, 64);
        if (ii < dg) acc4(a0, vbf[(long)c * 16 + sub]);
    }

    a0.x += (a1.x + a2.x) + a3.x;
    a0.y += (a1.y + a2.y) + a3.y;
    a0.z += (a1.z + a2.z) + a3.z;
    a0.w += (a1.w + a2.w) + a3.w;
    a0.x += __shfl_xor(a0.x, 16, 64); a0.y += __shfl_xor(a0.y, 16, 64);
    a0.z += __shfl_xor(a0.z, 16, 64); a0.w += __shfl_xor(a0.w, 16, 64);
    a0.x += __shfl_xor(a0.x, 32, 64); a0.y += __shfl_xor(a0.y, 32, 64);
    a0.z += __shfl_xor(a0.z, 32, 64); a0.w += __shfl_xor(a0.w, 32, 64);

    if (lane < 16) ((float4*)(sums + (long)v * DIM))[sub] = a0;
}

// Rare path: overflow edges (deg > CAP) — adds fp32 rows into sums.
__global__ void spill_kernel(const float* __restrict__ verts,
                             const int* __restrict__ spill,
                             const int* __restrict__ nspill,
                             float* __restrict__ sums) {
    const int lane = threadIdx.x & 63;
    const int wave = (int)((blockIdx.x * blockDim.x + threadIdx.x) >> 6);
    const int nwaves = (int)((gridDim.x * blockDim.x) >> 6);
    int n = *nspill; if (n > SPILL_MAX) n = SPILL_MAX;
    for (int i = wave; i < n; i += nwaves) {
        const int t = spill[2 * i], nb = spill[2 * i + 1];
        atomicAdd(&sums[(long)t * DIM + lane], verts[(long)nb * DIM + lane]);
    }
}

// ---------------------------------------------------------------------------
// MFMA matvec (R10, verified): out = [X|S]@[W0;W1]^T + b0 + deg*b1 via
// mfma_f32_16x16x32_bf16, one wave per 16-vertex tile, B-frags hoisted.
// ---------------------------------------------------------------------------
__global__ __launch_bounds__(256)
void matvec_mfma_kernel(const uint2* __restrict__ vbf,
                        const float* __restrict__ sums,
                        const float* __restrict__ w0,
                        const float* __restrict__ b0,
                        const float* __restrict__ w1,
                        const float* __restrict__ b1,
                        const int* __restrict__ cnt,
                        float* __restrict__ out) {
    const int lane = threadIdx.x & 63;
    const int quad = lane >> 4;
    const int n = lane & 15;
    const int wave = (int)((blockIdx.x * blockDim.x + threadIdx.x) >> 6);
    const int nwaves = (int)((gridDim.x * blockDim.x) >> 6);

    short8 B[4][4];
#pragma unroll
    for (int c = 0; c < 4; ++c) {
        const float* wsrc = (c < 2) ? w0 : w1;
        const int kb = (c & 1) * 32 + quad * 8;
#pragma unroll
        for (int t = 0; t < 4; ++t) {
            const int d = t * 16 + n;
            const float4 p = *(const float4*)(wsrc + d * DIM + kb);
            const float4 q = *(const float4*)(wsrc + d * DIM + kb + 4);
            B[c][t] = pack_bf8(p, q);
        }
    }
    float bias0[4], bias1[4];
#pragma unroll
    for (int t = 0; t < 4; ++t) { bias0[t] = b0[t * 16 + n]; bias1[t] = b1[t * 16 + n]; }

    const short8* vb8 = (const short8*)vbf;

    for (int tile = wave; tile < NTILE; tile += nwaves) {
        const int base = tile * 16;
        const long v = base + n;
        f32x4 acc[4] = {{0.f,0.f,0.f,0.f},{0.f,0.f,0.f,0.f},
                        {0.f,0.f,0.f,0.f},{0.f,0.f,0.f,0.f}};

#pragma unroll
        for (int c = 0; c < 2; ++c) {
            const short8 A = vb8[v * 8 + c * 4 + quad];
#pragma unroll
            for (int t = 0; t < 4; ++t)
                acc[t] = __builtin_amdgcn_mfma_f32_16x16x32_bf16(A, B[c][t], acc[t], 0, 0, 0);
        }
#pragma unroll
        for (int c = 2; c < 4; ++c) {
            const int kb = (c - 2) * 32 + quad * 8;
            const float4 p = *(const float4*)(sums + v * DIM + kb);
            const float4 q = *(const float4*)(sums + v * DIM + kb + 4);
            const short8 A = pack_bf8(p, q);
#pragma unroll
            for (int t = 0; t < 4; ++t)
                acc[t] = __builtin_amdgcn_mfma_f32_16x16x32_bf16(A, B[c][t], acc[t], 0, 0, 0);
        }
#pragma unroll
        for (int r = 0; r < 4; ++r) {
            const int row = base + quad * 4 + r;
            const float dg = (float)cnt[row];
#pragma unroll
            for (int t = 0; t < 4; ++t)
                out[(long)row * DIM + t * 16 + n] = acc[t][r] + fmaf(dg, bias1[t], bias0[t]);
        }
    }
}

// ==========================================================================

extern "C" void kernel_launch(void* const* d_in, const int* in_sizes, int n_in,
                              void* d_out, int out_size, void* d_ws, size_t ws_size,
                              hipStream_t stream) {
    const float* verts = (const float*)d_in[0];
    const int*   edges = (const int*)d_in[1];
    const float* w0_w  = (const float*)d_in[2];
    const float* w0_b  = (const float*)d_in[3];
    const float* w1_w  = (const float*)d_in[4];
    const float* w1_b  = (const float*)d_in[5];
    float* out = (float*)d_out;

    // Workspace: [sums fp32 V*D (25.6MB), ALIASED by bins 8*CAPB*4 (16.8MB)]
    //            | vbf V*D bf16 | col V*CAP | spill | cnt | bcur[8] | misc
    // bins die before gather writes sums (gather overwrites every row).
    char* p = (char*)d_ws;
    float*    sums = (float*)p;
    unsigned* bins = (unsigned*)p;  p += (size_t)NV * DIM * 4;
    uint2* vbf   = (uint2*)p;  p += (size_t)NV * DIM * 2;
    int* col     = (int*)p;    p += (size_t)NV * CAP * 4;
    int* spill   = (int*)p;    p += (size_t)SPILL_MAX * 8;
    int* cnt     = (int*)p;    p += (size_t)NV * 4;
    int* bcur    = (int*)p;    p += NXCD * 4;
    int* nspill  = (int*)p;
    int* flag    = nspill + 1;

    // zero cnt + bcur + nspill (+flag written by detect)
    hipMemsetAsync(cnt, 0, (size_t)NV * 4 + NXCD * 4 + 8, stream);
    detect_kernel<<<1, 64, 0, stream>>>(edges, flag);
    prep_kernel<<<(NV * (DIM / 4) + 255) / 256, 256, 0, stream>>>(verts, vbf);
    bin_kernel<<<ABLK, 256, 0, stream>>>(edges, bins, bcur, flag);
    fill_kernel<<<2048, 256, 0, stream>>>(bins, bcur, cnt, col, spill, nspill);
    gather_kernel<<<(NV + 3) / 4, 256, 0, stream>>>(vbf, cnt, col, sums);
    spill_kernel<<<64, 256, 0, stream>>>(verts, spill, nspill, sums);
    matvec_mfma_kernel<<<1563, 256, 0, stream>>>(vbf, sums, w0_w, w0_b,
                                                 w1_w, w1_b, cnt, out);
}